// Round 8
// baseline (193.990 us; speedup 1.0000x reference)
//
#include <hip/hip_runtime.h>

#define CIN   16
#define COUT  32
#define DIN   32
#define DOUT  30
#define NB    16

typedef __attribute__((ext_vector_type(8)))  short  short8;
typedef __attribute__((ext_vector_type(4)))  int    int4v;
typedef __attribute__((ext_vector_type(16))) float  f32x16;

static __device__ __forceinline__ unsigned short f2bf_rne(float f) {
    unsigned int u = __builtin_bit_cast(unsigned int, f);
    u += 0x7fffu + ((u >> 16) & 1u);
    return (unsigned short)(u >> 16);
}
static __device__ __forceinline__ float bf2f(unsigned short s) {
    unsigned int u = ((unsigned int)s) << 16;
    return __builtin_bit_cast(float, u);
}
// pull value from lane (bidx>>2) for all 4 dwords of a short8
static __device__ __forceinline__ short8 lane_pull(short8 v, int bidx) {
    int4v a = __builtin_bit_cast(int4v, v);
#pragma unroll
    for (int t = 0; t < 4; ++t)
        a[t] = __builtin_amdgcn_ds_bpermute(bidx, a[t]);
    return __builtin_bit_cast(short8, a);
}

// Single-kernel fused conv3d + epilogue.
// Static LDS: W-fragment table (bf16 hi/lo split, 55.3 KB) built cooperatively per
// block; x B-fragments built per-wave from global (kw=0) and shifted across lanes
// (ds_bpermute) for kw=1,2. Grid (ht 0..7, d2 0..14, b): 4 waves; wave wy computes
// output row h=4*ht+wy for d-outs 2*d2, 2*d2+1, all 32 co. 162 MFMAs/wave.
// C/D map (verified R3-R7): co=(r&3)+8*(r>>2)+4*(lane>>5), col=lane&31.
__global__ __launch_bounds__(256) void conv_wlds(
    const float* __restrict__ x,
    const float* __restrict__ wgt,
    const float* __restrict__ cbias,
    const float* __restrict__ scal,
    const float* __restrict__ bpar,
    float* __restrict__ out)
{
    __shared__ __align__(16) short swh[13824];   // 27 slices x 64 lanes x 8 bf16 (hi)
    __shared__ __align__(16) short swl[13824];   // (lo)
    __shared__ float sp[96];

    const int ht = blockIdx.x;     // h0 = 4*ht
    const int d2 = blockIdx.y;     // d0 = 2*d2
    const int b  = blockIdx.z;

    const int tid  = threadIdx.x;
    const int wy   = tid >> 6;
    const int lane = tid & 63;

    if (tid < 32) {
        sp[tid]      = cbias[tid];
        sp[32 + tid] = scal[tid];
        sp[64 + tid] = bpar[tid];
    }

    // ---- W-fragment table: entry e = s*64+l; lane l holds A[co=l&31][ci=(l>>5)*8+j] ----
    for (int e = tid; e < 1728; e += 256) {
        const int s = e >> 6, l = e & 63;
        const int co = l & 31, ci0 = (l >> 5) * 8;
        short8 vh, vl;
#pragma unroll
        for (int j = 0; j < 8; ++j) {
            float f = wgt[co * (CIN * 27) + (ci0 + j) * 27 + s];
            unsigned short hb = f2bf_rne(f);
            vh[j] = (short)hb;
            vl[j] = (short)f2bf_rne(f - bf2f(hb));
        }
        *(short8*)(swh + e * 8) = vh;
        *(short8*)(swl + e * 8) = vl;
    }
    __syncthreads();   // only barrier

    const int h0 = ht * 4, d0 = d2 * 2;
    const int h  = h0 + wy;
    if (h >= DOUT) return;          // ht=7: waves 2,3 idle (after barrier)

    const int n  = lane & 31;       // output w (kw=0 load column)
    const int oc = lane >> 5;       // ci octet
    // pull-from-lane+1 index (clamped at n=31; lanes n>=30 are pad, outputs masked)
    const int bidx = ((n < 31) ? (lane + 1) : lane) * 4;

    // x[b][ci][dd][hh][ww]: ci stride 32768, dd stride 1024, hh stride 32
    const float* xb = x + (size_t)b * (CIN * 32768) + oc * 8 * 32768 + d0 * 1024 + n;

    f32x16 acc0, acc1;
#pragma unroll
    for (int i = 0; i < 16; ++i) { acc0[i] = 0.0f; acc1[i] = 0.0f; }

#pragma unroll
    for (int kh = 0; kh < 3; ++kh) {
        const float* xr = xb + (h + kh) * 32;    // hin = h+kh <= 31
        // build kw=0 fragments for planes d0..d0+3
        short8 fh[4], fl[4];
#pragma unroll
        for (int q = 0; q < 4; ++q) {
            const float* xp = xr + q * 1024;
            float v[8];
#pragma unroll
            for (int j = 0; j < 8; ++j) v[j] = xp[j * 32768];   // ci = oc*8+j
            short8 vh, vl;
#pragma unroll
            for (int j = 0; j < 8; ++j) {
                unsigned short hb = f2bf_rne(v[j]);
                vh[j] = (short)hb;
                vl[j] = (short)f2bf_rne(v[j] - bf2f(hb));
            }
            fh[q] = vh; fl[q] = vl;
        }
#pragma unroll
        for (int kw = 0; kw < 3; ++kw) {
            if (kw > 0) {   // shift all frags: lane n takes lane n+1's value (w+=1)
#pragma unroll
                for (int q = 0; q < 4; ++q) {
                    fh[q] = lane_pull(fh[q], bidx);
                    fl[q] = lane_pull(fl[q], bidx);
                }
            }
#pragma unroll
            for (int kd = 0; kd < 3; ++kd) {
                const int s = kd * 9 + kh * 3 + kw;
                short8 ah = *(const short8*)(swh + (s * 64 + lane) * 8);
                short8 al = *(const short8*)(swl + (s * 64 + lane) * 8);
                acc0 = __builtin_amdgcn_mfma_f32_32x32x16_bf16(ah, fh[kd],     acc0, 0, 0, 0);
                acc1 = __builtin_amdgcn_mfma_f32_32x32x16_bf16(ah, fh[kd + 1], acc1, 0, 0, 0);
                acc0 = __builtin_amdgcn_mfma_f32_32x32x16_bf16(ah, fl[kd],     acc0, 0, 0, 0);
                acc1 = __builtin_amdgcn_mfma_f32_32x32x16_bf16(ah, fl[kd + 1], acc1, 0, 0, 0);
                acc0 = __builtin_amdgcn_mfma_f32_32x32x16_bf16(al, fh[kd],     acc0, 0, 0, 0);
                acc1 = __builtin_amdgcn_mfma_f32_32x32x16_bf16(al, fh[kd + 1], acc1, 0, 0, 0);
            }
        }
    }

    // ---- fused epilogue ----
    if (n < DOUT) {
        const int ob = b * (COUT * 27000) + h * 30 + n;
#pragma unroll
        for (int r = 0; r < 16; ++r) {
            const int co = (r & 3) + 8 * (r >> 2) + 4 * oc;
            float y0 = acc0[r] + sp[co];
            float t0 = y0 * sp[32 + co];
            float th0 = 1.0f - 2.0f / (__expf(2.0f * t0) + 1.0f);
            float z0 = th0 * sp[64 + co];
            out[ob + co * 27000 + d0 * 900] = 1.0f / (1.0f + __expf(-z0));

            float y1 = acc1[r] + sp[co];
            float t1 = y1 * sp[32 + co];
            float th1 = 1.0f - 2.0f / (__expf(2.0f * t1) + 1.0f);
            float z1 = th1 * sp[64 + co];
            out[ob + co * 27000 + (d0 + 1) * 900] = 1.0f / (1.0f + __expf(-z1));
        }
    }
}

extern "C" void kernel_launch(void* const* d_in, const int* in_sizes, int n_in,
                              void* d_out, int out_size, void* d_ws, size_t ws_size,
                              hipStream_t stream) {
    const float* x     = (const float*)d_in[0];
    const float* wgt   = (const float*)d_in[1];
    const float* cbias = (const float*)d_in[2];
    const float* scal  = (const float*)d_in[3];
    const float* bpar  = (const float*)d_in[4];
    float* out = (float*)d_out;

    // Deliberately a single plain launch: no d_ws, no hipFuncSetAttribute, no
    // second node, no cooperative launch — testing the ~64 us replay-gap theory.
    hipLaunchKernelGGL(conv_wlds, dim3(8, 15, NB), dim3(256), 0, stream,
                       x, wgt, cbias, scal, bpar, out);
}